// Round 7
// baseline (293.253 us; speedup 1.0000x reference)
//
#include <hip/hip_runtime.h>
#include <stdint.h>

typedef short bh8 __attribute__((ext_vector_type(8)));   // 8 bf16 (4 VGPR)
typedef float f32x4 __attribute__((ext_vector_type(4))); // MFMA accumulator

// ---------- helpers ----------
__device__ __forceinline__ float b2f(unsigned short u) {
    return __uint_as_float(((unsigned int)u) << 16);
}
__device__ __forceinline__ unsigned short f2b(float f) {
    unsigned int x = __float_as_uint(f);
    return (unsigned short)((x + 0x7FFFu + ((x >> 16) & 1u)) >> 16);  // RNE
}
__device__ __forceinline__ float ldf(const void* p, size_t i, int bf) {
    return bf ? b2f(((const unsigned short*)p)[i]) : ((const float*)p)[i];
}
__device__ __forceinline__ int ldi(const int* p, size_t i, int i64f) {
    return i64f ? p[2 * i] : p[i];
}
__device__ __forceinline__ void up8(uint4 v, float* d) {
    d[0] = b2f((unsigned short)(v.x)); d[1] = b2f((unsigned short)(v.x >> 16));
    d[2] = b2f((unsigned short)(v.y)); d[3] = b2f((unsigned short)(v.y >> 16));
    d[4] = b2f((unsigned short)(v.z)); d[5] = b2f((unsigned short)(v.z >> 16));
    d[6] = b2f((unsigned short)(v.w)); d[7] = b2f((unsigned short)(v.w >> 16));
}

// ---------- dtype detector ----------
__global__ void k_detect(const unsigned short* xs, const int* ei32, int* flags) {
    __shared__ int bad, nz;
    if (threadIdx.x == 0) { bad = 0; nz = 0; }
    __syncthreads();
    int t = threadIdx.x;
    int b = 0;
    for (int i = t; i < 4096; i += 256) {
        unsigned e = (xs[i] >> 7) & 0xFF;
        if (e >= 0xE2) b = 1;
    }
    if (b) atomicOr(&bad, 1);
    int n = 0;
    for (int i = t; i < 512; i += 256) {
        if (ei32[2 * i + 1] != 0) n = 1;
    }
    if (n) atomicOr(&nz, 1);
    __syncthreads();
    if (t == 0) { flags[0] = bad ? 0 : 1; flags[1] = nz ? 0 : 1; }
}

// ---------- W1 prep: bf16 transposed Wt[n][k], one-time ----------
__global__ void k_prepW(const void* __restrict__ W1, unsigned short* __restrict__ Wt,
                        const int* __restrict__ flags) {
    int bf = flags[0];
    for (int idx = threadIdx.x; idx < 16384; idx += 256) {
        int k = idx >> 7, n = idx & 127;
        Wt[n * 128 + k] = bf ? ((const unsigned short*)W1)[idx]
                             : f2b(((const float*)W1)[idx]);
    }
}

// ---------- histogram (standalone: no LDS -> full occupancy) ----------
__global__ void k_hist(const int* __restrict__ ei, int* __restrict__ counts,
                       int* __restrict__ eoff, const int* __restrict__ flags,
                       int E, int Et) {
    int e = blockIdx.x * 256 + threadIdx.x;
    if (e >= Et) return;
    int i64f = flags[1];
    int d = (e < E) ? ldi(ei, (size_t)E + e, i64f) : (e - E);
    eoff[e] = atomicAdd(&counts[d], 1);
}

// ---------- scan ----------
__global__ void k_scan1(const int* __restrict__ counts, int* __restrict__ excl,
                        int* __restrict__ bsums, int N) {
    __shared__ int sd[256];
    int t = threadIdx.x;
    int base = blockIdx.x * 1024 + t * 4;
    int v0 = (base + 0 < N) ? counts[base + 0] : 0;
    int v1 = (base + 1 < N) ? counts[base + 1] : 0;
    int v2 = (base + 2 < N) ? counts[base + 2] : 0;
    int v3 = (base + 3 < N) ? counts[base + 3] : 0;
    int ls = v0 + v1 + v2 + v3;
    sd[t] = ls; __syncthreads();
    for (int off = 1; off < 256; off <<= 1) {
        int x = 0;
        if (t >= off) x = sd[t - off];
        __syncthreads();
        if (t >= off) sd[t] += x;
        __syncthreads();
    }
    int incl = sd[t];
    int ex = incl - ls;
    if (t == 255) bsums[blockIdx.x] = incl;
    if (base + 0 < N) excl[base + 0] = ex; ex += v0;
    if (base + 1 < N) excl[base + 1] = ex; ex += v1;
    if (base + 2 < N) excl[base + 2] = ex; ex += v2;
    if (base + 3 < N) excl[base + 3] = ex;
}

__global__ void k_scan2(int* __restrict__ bsums, int NB) {
    int run = 0;
    for (int i = 0; i < NB; i++) { int t = bsums[i]; bsums[i] = run; run += t; }
}

__global__ void k_scan3(int* __restrict__ rowptr, const int* __restrict__ bsums, int N, int Et) {
    int t = threadIdx.x;
    int base = blockIdx.x * 1024 + t * 4;
    int off = bsums[blockIdx.x];
    #pragma unroll
    for (int j = 0; j < 4; j++) { int i = base + j; if (i < N) rowptr[i] += off; }
    if (blockIdx.x == 0 && t == 0) rowptr[N] = Et;
}

// ---------- scatter (atomic-free) ----------
__global__ void k_scatter(const int* __restrict__ ei, const int* __restrict__ rowptr,
                          const int* __restrict__ eoff, int* __restrict__ esrc,
                          const int* __restrict__ flags, int E, int Et) {
    int e = blockIdx.x * 256 + threadIdx.x;
    if (e >= Et) return;
    int i64f = flags[1];
    int s, d;
    if (e < E) { s = ldi(ei, (size_t)e, i64f); d = ldi(ei, (size_t)E + e, i64f); }
    else       { s = d = e - E; }
    esrc[rowptr[d] + eoff[e]] = s;
}

// ---------- layer 1 GEMM, MFMA: xh1 = x @ W1 via D' = Wt x^T ----------
// 64 rows/block; Wt (bf16 [128][128]) staged to padded LDS; X converted to bf16.
// Fragments (verified layouts): A[m=lane&15][k=quad*8+j]; C/D col=lane&15, row=quad*4+reg.
__global__ __launch_bounds__(256)
void k_gemm1m(const void* __restrict__ xr, const unsigned short* __restrict__ Wt,
              const void* __restrict__ aSr, const void* __restrict__ aDr,
              unsigned int* __restrict__ xh1b, float* __restrict__ a_src,
              float* __restrict__ a_dst, const int* __restrict__ flags, int N) {
    __shared__ unsigned short Xl[64 * 136];   // +8 pad: stride 272B -> 2-way banks (free)
    __shared__ unsigned short Wl[128 * 136];
    __shared__ float aSf[128], aDf[128];
    int t = threadIdx.x;
    int bf = flags[0];
    int r0 = blockIdx.x * 64;
    if (t < 128) { aSf[t] = ldf(aSr, t, bf); aDf[t] = ldf(aDr, t, bf); }
    // stage Wt (2048 uint4)
    #pragma unroll
    for (int i = 0; i < 8; i++) {
        int idx = t + 256 * i;
        int row = idx >> 4, c16 = idx & 15;
        *(uint4*)&Wl[row * 136 + c16 * 8] = ((const uint4*)Wt)[idx];
    }
    // stage X -> bf16
    if (bf) {
        const uint4* Xv = (const uint4*)((const unsigned short*)xr + (size_t)r0 * 128);
        #pragma unroll
        for (int i = 0; i < 4; i++) {
            int idx = t + 256 * i;                  // 1024 uint4
            int row = idx >> 4, c16 = idx & 15;
            uint4 v = (r0 + row < N) ? Xv[idx] : uint4{0, 0, 0, 0};
            *(uint4*)&Xl[row * 136 + c16 * 8] = v;
        }
    } else {
        const float4* Xv = (const float4*)((const float*)xr + (size_t)r0 * 128);
        #pragma unroll
        for (int i = 0; i < 8; i++) {
            int idx = t + 256 * i;                  // 2048 float4
            int row = idx >> 5, c4 = idx & 31;
            float4 v = (r0 + row < N) ? Xv[idx] : float4{0.f, 0.f, 0.f, 0.f};
            uint2 pk;
            pk.x = (unsigned int)f2b(v.x) | ((unsigned int)f2b(v.y) << 16);
            pk.y = (unsigned int)f2b(v.z) | ((unsigned int)f2b(v.w) << 16);
            *(uint2*)&Xl[row * 136 + c4 * 4] = pk;
        }
    }
    __syncthreads();
    int w = t >> 6, lane = t & 63;
    int m16 = lane & 15, quad = lane >> 4;
    f32x4 acc[8];
    #pragma unroll
    for (int ct = 0; ct < 8; ct++) acc[ct] = (f32x4){0.f, 0.f, 0.f, 0.f};
    #pragma unroll
    for (int kb = 0; kb < 4; kb++) {
        bh8 xf = *(const bh8*)&Xl[(w * 16 + m16) * 136 + kb * 32 + quad * 8];
        #pragma unroll
        for (int ct = 0; ct < 8; ct++) {
            bh8 wf = *(const bh8*)&Wl[(ct * 16 + m16) * 136 + kb * 32 + quad * 8];
            acc[ct] = __builtin_amdgcn_mfma_f32_16x16x32_bf16(wf, xf, acc[ct], 0, 0, 0);
        }
    }
    __syncthreads();   // done reading Xl; reuse as output tile [64][136] bf16
    // D'[n_local = quad*4+reg][m = lane&15]: row m16 (+w*16), cols ct*16 + quad*4 + reg
    {
        int orow = w * 16 + m16;
        #pragma unroll
        for (int ct = 0; ct < 8; ct++) {
            uint2 pk;
            pk.x = (unsigned int)f2b(acc[ct][0]) | ((unsigned int)f2b(acc[ct][1]) << 16);
            pk.y = (unsigned int)f2b(acc[ct][2]) | ((unsigned int)f2b(acc[ct][3]) << 16);
            *(uint2*)&Xl[orow * 136 + ct * 16 + quad * 4] = pk;
        }
    }
    __syncthreads();
    // attention coefficients: thread -> (row = t>>2, heads {2*(t&3), 2*(t&3)+1})
    {
        int r = t >> 2, hp = t & 3;
        if (r0 + r < N) {
            #pragma unroll
            for (int hh = 0; hh < 2; hh++) {
                int h = hp * 2 + hh;
                float s = 0.f, d = 0.f;
                #pragma unroll
                for (int c = 0; c < 16; c++) {
                    float xv = b2f(Xl[r * 136 + h * 16 + c]);
                    s += xv * aSf[h * 16 + c];
                    d += xv * aDf[h * 16 + c];
                }
                a_src[(size_t)(r0 + r) * 8 + h] = s;
                a_dst[(size_t)(r0 + r) * 8 + h] = d;
            }
        }
    }
    // coalesced xh1b write (1024 uint4)
    #pragma unroll
    for (int i = 0; i < 4; i++) {
        int idx = t + 256 * i;
        int row = idx >> 4, c16 = idx & 15;
        if (r0 + row < N)
            ((uint4*)xh1b)[(size_t)(r0 + row) * 16 + c16] =
                *(const uint4*)&Xl[row * 136 + c16 * 8];
    }
}

// ---------- layer 1 softmax-aggregate: one wave per dst, no-max softmax, unroll-8 ----------
__global__ __launch_bounds__(256)
void k_agg1(const int* __restrict__ rowptr, const int* __restrict__ esrc,
            const float* __restrict__ a_src, const float* __restrict__ a_dst,
            const unsigned int* __restrict__ xh1b, const void* __restrict__ b1,
            unsigned int* __restrict__ h1b, const int* __restrict__ flags, int N) {
    int node = blockIdx.x * 4 + (threadIdx.x >> 6);
    int lane = threadIdx.x & 63;
    if (node >= N) return;
    int bf = flags[0];
    int r0 = rowptr[node], r1 = rowptr[node + 1];
    int h8  = lane & 7;
    int q   = lane >> 3;
    float adst = a_dst[node * 8 + h8];
    float den = 0.f, acc0 = 0.f, acc1 = 0.f;
    for (int e = r0; e < r1; e += 8) {
        int idx = e + q;
        bool valid = idx < r1;
        int s_mine = valid ? esrc[idx] : 0;
        float v = (valid ? a_src[(size_t)s_mine * 8 + h8] : 0.f) + adst;
        v = v > 0.f ? v : 0.2f * v;
        float ex = valid ? __expf(v) : 0.f;
        den += ex;
        #pragma unroll
        for (int q2 = 0; q2 < 8; q2++) {
            int   s_q  = __shfl(s_mine, q2 * 8);
            float ex_q = __shfl(ex, q2 * 8 + q);
            unsigned int wv = xh1b[(size_t)s_q * 64 + lane];
            acc0 += ex_q * b2f((unsigned short)wv);
            acc1 += ex_q * b2f((unsigned short)(wv >> 16));
        }
    }
    den += __shfl_xor(den, 8);
    den += __shfl_xor(den, 16);
    den += __shfl_xor(den, 32);
    float dA = __shfl(den, q) + 1e-16f;
    float o0 = acc0 / dA + ldf(b1, 2 * lane, bf);
    float o1 = acc1 / dA + ldf(b1, 2 * lane + 1, bf);
    o0 = o0 > 0.f ? o0 : expm1f(o0);
    o1 = o1 > 0.f ? o1 : expm1f(o1);
    h1b[(size_t)node * 64 + lane] =
        (unsigned int)f2b(o0) | ((unsigned int)f2b(o1) << 16);
}

// ---------- layer 2 GEMM (fused att coeffs): xh2b(bf16) = h1 @ W2 ----------
__global__ __launch_bounds__(256)
void k_gemm2(const unsigned int* __restrict__ h1b, const void* __restrict__ Wr,
             const void* __restrict__ aSr, const void* __restrict__ aDr,
             unsigned int* __restrict__ xh2b, float* __restrict__ a_src,
             float* __restrict__ a_dst, const int* __restrict__ flags, int N) {
    __shared__ float Wl[128 * 64];
    __shared__ float Xl[32 * 129];
    int t = threadIdx.x;
    int bf = flags[0];
    int r0 = blockIdx.x * 32;
    if (bf) {
        const uint4* Wv = (const uint4*)Wr;
        #pragma unroll
        for (int i = 0; i < 4; i++) { int idx = t + 256 * i; up8(Wv[idx], &Wl[idx * 8]); }
    } else {
        const float4* Wv = (const float4*)Wr;
        #pragma unroll
        for (int i = 0; i < 8; i++) { int idx = t + 256 * i; ((float4*)Wl)[idx] = Wv[idx]; }
    }
    {
        const uint4* Xv = (const uint4*)h1b;
        #pragma unroll
        for (int i = 0; i < 2; i++) {
            int idx = t + 256 * i;
            int row = idx >> 4, col = (idx & 15) * 8;
            uint4 v = (r0 + row < N) ? Xv[(size_t)(r0 + row) * 16 + (idx & 15)] : uint4{0,0,0,0};
            float tmp[8]; up8(v, tmp);
            #pragma unroll
            for (int j = 0; j < 8; j++) Xl[row * 129 + col + j] = tmp[j];
        }
    }
    __syncthreads();
    int rg = t >> 4, cg = t & 15;
    float4 acc[2] = {{0,0,0,0},{0,0,0,0}};
    #pragma unroll 4
    for (int k = 0; k < 128; k++) {
        float4 w = *(const float4*)&Wl[k * 64 + (cg << 2)];
        #pragma unroll
        for (int i = 0; i < 2; i++) {
            float xv = Xl[(rg * 2 + i) * 129 + k];
            acc[i].x += xv * w.x; acc[i].y += xv * w.y;
            acc[i].z += xv * w.z; acc[i].w += xv * w.w;
        }
    }
    float aS0 = ldf(aSr, cg*4+0, bf), aS1 = ldf(aSr, cg*4+1, bf);
    float aS2 = ldf(aSr, cg*4+2, bf), aS3 = ldf(aSr, cg*4+3, bf);
    float aD0 = ldf(aDr, cg*4+0, bf), aD1 = ldf(aDr, cg*4+1, bf);
    float aD2 = ldf(aDr, cg*4+2, bf), aD3 = ldf(aDr, cg*4+3, bf);
    #pragma unroll
    for (int i = 0; i < 2; i++) {
        int row = r0 + rg * 2 + i;
        float ps = acc[i].x*aS0 + acc[i].y*aS1 + acc[i].z*aS2 + acc[i].w*aS3;
        float pd = acc[i].x*aD0 + acc[i].y*aD1 + acc[i].z*aD2 + acc[i].w*aD3;
        ps += __shfl_xor(ps, 1); ps += __shfl_xor(ps, 2);
        ps += __shfl_xor(ps, 4); ps += __shfl_xor(ps, 8);
        pd += __shfl_xor(pd, 1); pd += __shfl_xor(pd, 2);
        pd += __shfl_xor(pd, 4); pd += __shfl_xor(pd, 8);
        if (row < N) {
            if (cg == 0) { a_src[row] = ps; a_dst[row] = pd; }
            uint2 pk;
            pk.x = (unsigned int)f2b(acc[i].x) | ((unsigned int)f2b(acc[i].y) << 16);
            pk.y = (unsigned int)f2b(acc[i].z) | ((unsigned int)f2b(acc[i].w) << 16);
            ((uint2*)xh2b)[(size_t)row * 16 + cg] = pk;
        }
    }
}

// ---------- layer 2 softmax-aggregate -> output (no-max softmax, unroll-8) ----------
__global__ __launch_bounds__(256)
void k_agg2(const int* __restrict__ rowptr, const int* __restrict__ esrc,
            const float* __restrict__ a_src, const float* __restrict__ a_dst,
            const unsigned int* __restrict__ xh2b, const void* __restrict__ bias,
            void* __restrict__ out, const int* __restrict__ flags, int N) {
    int node = blockIdx.x * 4 + (threadIdx.x >> 6);
    int lane = threadIdx.x & 63;
    if (node >= N) return;
    int bf = flags[0];
    int r0 = rowptr[node], r1 = rowptr[node + 1];
    int q = lane >> 3;
    float adst = a_dst[node];
    const unsigned short* xs = (const unsigned short*)xh2b;
    float den = 0.f, acc = 0.f;
    for (int e = r0; e < r1; e += 8) {
        int idx = e + q;
        bool valid = idx < r1;
        int s_mine = valid ? esrc[idx] : 0;
        float v = (valid ? a_src[s_mine] : 0.f) + adst;
        v = v > 0.f ? v : 0.2f * v;
        float ex = valid ? __expf(v) : 0.f;
        den += ex;
        #pragma unroll
        for (int q2 = 0; q2 < 8; q2++) {
            int   s_q  = __shfl(s_mine, q2 * 8);
            float ex_q = __shfl(ex, q2 * 8);
            acc += ex_q * b2f(xs[(size_t)s_q * 64 + lane]);
        }
    }
    den += __shfl_xor(den, 8);
    den += __shfl_xor(den, 16);
    den += __shfl_xor(den, 32);
    float o = acc / (den + 1e-16f) + ldf(bias, lane, bf);
    size_t oi = (size_t)node * 64 + lane;
    if (bf) ((unsigned short*)out)[oi] = f2b(o);
    else    ((float*)out)[oi] = o;
}

// ---------- launch ----------
extern "C" void kernel_launch(void* const* d_in, const int* in_sizes, int n_in,
                              void* d_out, int out_size, void* d_ws, size_t ws_size,
                              hipStream_t stream) {
    const void* x   = d_in[0];
    const int*  ei  = (const int*)d_in[1];
    const void* W1  = d_in[2];
    const void* aS1 = d_in[3];
    const void* aD1 = d_in[4];
    const void* b1  = d_in[5];
    const void* W2  = d_in[6];
    const void* aS2 = d_in[7];
    const void* aD2 = d_in[8];
    const void* b2v = d_in[9];

    const int N  = in_sizes[0] / 128;   // 50000
    const int E  = in_sizes[1] / 2;     // 800000
    const int Et = E + N;

    char* p = (char*)d_ws;
    auto alloc = [&](size_t bytes) -> char* {
        char* q = p; p += (bytes + 255) & ~(size_t)255; return q;
    };
    unsigned int* xh1b = (unsigned int*)alloc((size_t)N * 64 * 4);
    unsigned int* h1b  = (unsigned int*)alloc((size_t)N * 64 * 4);
    unsigned int* xh2b = (unsigned int*)alloc((size_t)N * 32 * 4);
    float* as1  = (float*)alloc((size_t)N * 8 * 4);
    float* ad1  = (float*)alloc((size_t)N * 8 * 4);
    float* as2  = (float*)alloc((size_t)N * 4);
    float* ad2  = (float*)alloc((size_t)N * 4);
    int* counts = (int*)alloc((size_t)N * 4);
    int* rowptr = (int*)alloc((size_t)(N + 1) * 4);
    int* eoff   = (int*)alloc((size_t)Et * 4);
    int* esrc   = (int*)alloc((size_t)Et * 4);
    int* bsums  = (int*)alloc(64 * 4);
    int* flags  = (int*)alloc(16 * 4);
    unsigned short* Wt1 = (unsigned short*)alloc(128 * 128 * 2);

    k_detect<<<1, 256, 0, stream>>>((const unsigned short*)x, ei, flags);
    hipMemsetAsync(counts, 0, (size_t)N * 4, stream);
    k_prepW<<<1, 256, 0, stream>>>(W1, Wt1, flags);

    int HB = (Et + 255) / 256;
    k_hist<<<HB, 256, 0, stream>>>(ei, counts, eoff, flags, E, Et);
    int NB = (N + 1023) / 1024;
    k_scan1<<<NB, 256, 0, stream>>>(counts, rowptr, bsums, N);
    k_scan2<<<1, 1, 0, stream>>>(bsums, NB);
    k_scan3<<<NB, 256, 0, stream>>>(rowptr, bsums, N, Et);
    k_scatter<<<HB, 256, 0, stream>>>(ei, rowptr, eoff, esrc, flags, E, Et);

    k_gemm1m<<<(N + 63) / 64, 256, 0, stream>>>(x, Wt1, aS1, aD1, xh1b, as1, ad1, flags, N);
    k_agg1<<<(N + 3) / 4, 256, 0, stream>>>(rowptr, esrc, as1, ad1, xh1b, b1, h1b, flags, N);
    int NGB = (N + 31) / 32;
    k_gemm2<<<NGB, 256, 0, stream>>>(h1b, W2, aS2, aD2, xh2b, as2, ad2, flags, N);
    k_agg2<<<(N + 3) / 4, 256, 0, stream>>>(rowptr, esrc, as2, ad2, xh2b, b2v, d_out, flags, N);
}

// Round 8
// 273.328 us; speedup vs baseline: 1.0729x; 1.0729x over previous
//
#include <hip/hip_runtime.h>
#include <stdint.h>

typedef short bh8 __attribute__((ext_vector_type(8)));   // 8 bf16 (4 VGPR)
typedef float f32x4 __attribute__((ext_vector_type(4))); // MFMA accumulator

// ---------- helpers ----------
__device__ __forceinline__ float b2f(unsigned short u) {
    return __uint_as_float(((unsigned int)u) << 16);
}
__device__ __forceinline__ unsigned short f2b(float f) {
    unsigned int x = __float_as_uint(f);
    return (unsigned short)((x + 0x7FFFu + ((x >> 16) & 1u)) >> 16);  // RNE
}
__device__ __forceinline__ float ldf(const void* p, size_t i, int bf) {
    return bf ? b2f(((const unsigned short*)p)[i]) : ((const float*)p)[i];
}
__device__ __forceinline__ int ldi(const int* p, size_t i, int i64f) {
    return i64f ? p[2 * i] : p[i];
}
__device__ __forceinline__ void up8(uint4 v, float* d) {
    d[0] = b2f((unsigned short)(v.x)); d[1] = b2f((unsigned short)(v.x >> 16));
    d[2] = b2f((unsigned short)(v.y)); d[3] = b2f((unsigned short)(v.y >> 16));
    d[4] = b2f((unsigned short)(v.z)); d[5] = b2f((unsigned short)(v.z >> 16));
    d[6] = b2f((unsigned short)(v.w)); d[7] = b2f((unsigned short)(v.w >> 16));
}

// ---------- dtype detector + W1 transpose prep (fused, 1 block) ----------
__global__ void k_detect(const unsigned short* xs, const int* ei32, int* flags,
                         const void* __restrict__ W1, unsigned short* __restrict__ Wt) {
    __shared__ int bad, nz;
    if (threadIdx.x == 0) { bad = 0; nz = 0; }
    __syncthreads();
    int t = threadIdx.x;
    int b = 0;
    for (int i = t; i < 4096; i += 256) {
        unsigned e = (xs[i] >> 7) & 0xFF;
        if (e >= 0xE2) b = 1;
    }
    if (b) atomicOr(&bad, 1);
    int n = 0;
    for (int i = t; i < 512; i += 256) {
        if (ei32[2 * i + 1] != 0) n = 1;
    }
    if (n) atomicOr(&nz, 1);
    __syncthreads();
    if (t == 0) { flags[0] = bad ? 0 : 1; flags[1] = nz ? 0 : 1; }
    int bf = bad ? 0 : 1;
    for (int idx = t; idx < 16384; idx += 256) {
        int k = idx >> 7, nn = idx & 127;
        Wt[nn * 128 + k] = bf ? ((const unsigned short*)W1)[idx]
                              : f2b(((const float*)W1)[idx]);
    }
}

// ---------- histogram (standalone: no LDS -> full occupancy) ----------
__global__ void k_hist(const int* __restrict__ ei, int* __restrict__ counts,
                       int* __restrict__ eoff, const int* __restrict__ flags,
                       int E, int Et) {
    int e = blockIdx.x * 256 + threadIdx.x;
    if (e >= Et) return;
    int i64f = flags[1];
    int d = (e < E) ? ldi(ei, (size_t)E + e, i64f) : (e - E);
    eoff[e] = atomicAdd(&counts[d], 1);
}

// ---------- scan (2 kernels: per-block excl scan; then add block-prefix) ----------
__global__ void k_scan1(const int* __restrict__ counts, int* __restrict__ excl,
                        int* __restrict__ bsums, int N) {
    __shared__ int sd[256];
    int t = threadIdx.x;
    int base = blockIdx.x * 1024 + t * 4;
    int v0 = (base + 0 < N) ? counts[base + 0] : 0;
    int v1 = (base + 1 < N) ? counts[base + 1] : 0;
    int v2 = (base + 2 < N) ? counts[base + 2] : 0;
    int v3 = (base + 3 < N) ? counts[base + 3] : 0;
    int ls = v0 + v1 + v2 + v3;
    sd[t] = ls; __syncthreads();
    for (int off = 1; off < 256; off <<= 1) {
        int x = 0;
        if (t >= off) x = sd[t - off];
        __syncthreads();
        if (t >= off) sd[t] += x;
        __syncthreads();
    }
    int incl = sd[t];
    int ex = incl - ls;
    if (t == 255) bsums[blockIdx.x] = incl;   // block TOTAL (not prefix)
    if (base + 0 < N) excl[base + 0] = ex; ex += v0;
    if (base + 1 < N) excl[base + 1] = ex; ex += v1;
    if (base + 2 < N) excl[base + 2] = ex; ex += v2;
    if (base + 3 < N) excl[base + 3] = ex;
}

__global__ void k_scan3(int* __restrict__ rowptr, const int* __restrict__ bsums,
                        int N, int Et) {
    int t = threadIdx.x;
    int base = blockIdx.x * 1024 + t * 4;
    int off = 0;
    for (int i = 0; i < (int)blockIdx.x; i++) off += bsums[i];   // <=48 iters
    #pragma unroll
    for (int j = 0; j < 4; j++) { int i = base + j; if (i < N) rowptr[i] += off; }
    if (blockIdx.x == 0 && t == 0) rowptr[N] = Et;
}

// ---------- scatter (atomic-free) ----------
__global__ void k_scatter(const int* __restrict__ ei, const int* __restrict__ rowptr,
                          const int* __restrict__ eoff, int* __restrict__ esrc,
                          const int* __restrict__ flags, int E, int Et) {
    int e = blockIdx.x * 256 + threadIdx.x;
    if (e >= Et) return;
    int i64f = flags[1];
    int s, d;
    if (e < E) { s = ldi(ei, (size_t)e, i64f); d = ldi(ei, (size_t)E + e, i64f); }
    else       { s = d = e - E; }
    esrc[rowptr[d] + eoff[e]] = s;
}

// ---------- layer 1 GEMM, MFMA: xh1 = x @ W1 via D' = Wt x^T ----------
__global__ __launch_bounds__(256)
void k_gemm1m(const void* __restrict__ xr, const unsigned short* __restrict__ Wt,
              const void* __restrict__ aSr, const void* __restrict__ aDr,
              unsigned int* __restrict__ xh1b, float* __restrict__ a_src,
              float* __restrict__ a_dst, const int* __restrict__ flags, int N) {
    __shared__ unsigned short Xl[64 * 136];   // +8 pad: 2-way bank alias (free)
    __shared__ unsigned short Wl[128 * 136];
    __shared__ float aSf[128], aDf[128];
    int t = threadIdx.x;
    int bf = flags[0];
    int r0 = blockIdx.x * 64;
    if (t < 128) { aSf[t] = ldf(aSr, t, bf); aDf[t] = ldf(aDr, t, bf); }
    #pragma unroll
    for (int i = 0; i < 8; i++) {
        int idx = t + 256 * i;
        int row = idx >> 4, c16 = idx & 15;
        *(uint4*)&Wl[row * 136 + c16 * 8] = ((const uint4*)Wt)[idx];
    }
    if (bf) {
        const uint4* Xv = (const uint4*)((const unsigned short*)xr + (size_t)r0 * 128);
        #pragma unroll
        for (int i = 0; i < 4; i++) {
            int idx = t + 256 * i;
            int row = idx >> 4, c16 = idx & 15;
            uint4 v = (r0 + row < N) ? Xv[idx] : uint4{0, 0, 0, 0};
            *(uint4*)&Xl[row * 136 + c16 * 8] = v;
        }
    } else {
        const float4* Xv = (const float4*)((const float*)xr + (size_t)r0 * 128);
        #pragma unroll
        for (int i = 0; i < 8; i++) {
            int idx = t + 256 * i;
            int row = idx >> 5, c4 = idx & 31;
            float4 v = (r0 + row < N) ? Xv[idx] : float4{0.f, 0.f, 0.f, 0.f};
            uint2 pk;
            pk.x = (unsigned int)f2b(v.x) | ((unsigned int)f2b(v.y) << 16);
            pk.y = (unsigned int)f2b(v.z) | ((unsigned int)f2b(v.w) << 16);
            *(uint2*)&Xl[row * 136 + c4 * 4] = pk;
        }
    }
    __syncthreads();
    int w = t >> 6, lane = t & 63;
    int m16 = lane & 15, quad = lane >> 4;
    f32x4 acc[8];
    #pragma unroll
    for (int ct = 0; ct < 8; ct++) acc[ct] = (f32x4){0.f, 0.f, 0.f, 0.f};
    #pragma unroll
    for (int kb = 0; kb < 4; kb++) {
        bh8 xf = *(const bh8*)&Xl[(w * 16 + m16) * 136 + kb * 32 + quad * 8];
        #pragma unroll
        for (int ct = 0; ct < 8; ct++) {
            bh8 wf = *(const bh8*)&Wl[(ct * 16 + m16) * 136 + kb * 32 + quad * 8];
            acc[ct] = __builtin_amdgcn_mfma_f32_16x16x32_bf16(wf, xf, acc[ct], 0, 0, 0);
        }
    }
    __syncthreads();
    {
        int orow = w * 16 + m16;
        #pragma unroll
        for (int ct = 0; ct < 8; ct++) {
            uint2 pk;
            pk.x = (unsigned int)f2b(acc[ct][0]) | ((unsigned int)f2b(acc[ct][1]) << 16);
            pk.y = (unsigned int)f2b(acc[ct][2]) | ((unsigned int)f2b(acc[ct][3]) << 16);
            *(uint2*)&Xl[orow * 136 + ct * 16 + quad * 4] = pk;
        }
    }
    __syncthreads();
    {
        int r = t >> 2, hp = t & 3;
        if (r0 + r < N) {
            #pragma unroll
            for (int hh = 0; hh < 2; hh++) {
                int h = hp * 2 + hh;
                float s = 0.f, d = 0.f;
                #pragma unroll
                for (int c = 0; c < 16; c++) {
                    float xv = b2f(Xl[r * 136 + h * 16 + c]);
                    s += xv * aSf[h * 16 + c];
                    d += xv * aDf[h * 16 + c];
                }
                a_src[(size_t)(r0 + r) * 8 + h] = s;
                a_dst[(size_t)(r0 + r) * 8 + h] = d;
            }
        }
    }
    #pragma unroll
    for (int i = 0; i < 4; i++) {
        int idx = t + 256 * i;
        int row = idx >> 4, c16 = idx & 15;
        if (r0 + row < N)
            ((uint4*)xh1b)[(size_t)(r0 + row) * 16 + c16] =
                *(const uint4*)&Xl[row * 136 + c16 * 8];
    }
}

// ---------- layer 1 softmax-aggregate: readlane s, saddr gathers, prefetched ----------
__global__ __launch_bounds__(256)
void k_agg1(const int* __restrict__ rowptr, const int* __restrict__ esrc,
            const float* __restrict__ a_src, const float* __restrict__ a_dst,
            const unsigned int* __restrict__ xh1b, const void* __restrict__ b1,
            unsigned int* __restrict__ h1b, const int* __restrict__ flags, int N) {
    int node = blockIdx.x * 4 + (threadIdx.x >> 6);
    int lane = threadIdx.x & 63;
    if (node >= N) return;
    int bf = flags[0];
    int r0 = rowptr[node], r1 = rowptr[node + 1];
    int h8 = lane & 7;    // head this lane scores
    int q  = lane >> 3;   // edge slot this lane covers; also head of my channels
    float adst = a_dst[node * 8 + h8];
    // prefetch chunk 0
    int pidx = r0 + q;
    bool pval = pidx < r1;
    int   s_next = pval ? esrc[pidx] : 0;
    float a_next = pval ? a_src[(size_t)s_next * 8 + h8] : 0.f;
    float den = 0.f, acc0 = 0.f, acc1 = 0.f;
    for (int e = r0; e < r1; e += 8) {
        int   s_mine = s_next;
        float a_cur  = a_next;
        bool  vcur   = (e + q) < r1;
        // prefetch next chunk (hides esrc->a_src chain behind this chunk's gathers)
        int idx2 = e + 8 + q;
        bool v2 = idx2 < r1;
        s_next = v2 ? esrc[idx2] : 0;
        a_next = v2 ? a_src[(size_t)s_next * 8 + h8] : 0.f;
        float v = a_cur + adst;
        v = v > 0.f ? v : 0.2f * v;
        float ex = vcur ? __expf(v) : 0.f;
        den += ex;
        #pragma unroll
        for (int q2 = 0; q2 < 8; q2++) {
            int   s_q  = __builtin_amdgcn_readlane(s_mine, q2 * 8);  // SGPR, no LDS op
            float ex_q = __shfl(ex, q2 * 8 + q);                     // 1 bpermute
            const unsigned int* rowp = xh1b + (size_t)s_q * 64;      // SGPR base
            unsigned int wv = rowp[lane];
            acc0 += ex_q * b2f((unsigned short)wv);
            acc1 += ex_q * b2f((unsigned short)(wv >> 16));
        }
    }
    den += __shfl_xor(den, 8);
    den += __shfl_xor(den, 16);
    den += __shfl_xor(den, 32);
    float dA = __shfl(den, q) + 1e-16f;   // lane q holds h8==q
    float o0 = acc0 / dA + ldf(b1, 2 * lane, bf);
    float o1 = acc1 / dA + ldf(b1, 2 * lane + 1, bf);
    o0 = o0 > 0.f ? o0 : expm1f(o0);   // ELU
    o1 = o1 > 0.f ? o1 : expm1f(o1);
    h1b[(size_t)node * 64 + lane] =
        (unsigned int)f2b(o0) | ((unsigned int)f2b(o1) << 16);
}

// ---------- layer 2 GEMM (fused att coeffs): xh2b(bf16) = h1 @ W2 ----------
__global__ __launch_bounds__(256)
void k_gemm2(const unsigned int* __restrict__ h1b, const void* __restrict__ Wr,
             const void* __restrict__ aSr, const void* __restrict__ aDr,
             unsigned int* __restrict__ xh2b, float* __restrict__ a_src,
             float* __restrict__ a_dst, const int* __restrict__ flags, int N) {
    __shared__ float Wl[128 * 64];
    __shared__ float Xl[32 * 129];
    int t = threadIdx.x;
    int bf = flags[0];
    int r0 = blockIdx.x * 32;
    if (bf) {
        const uint4* Wv = (const uint4*)Wr;
        #pragma unroll
        for (int i = 0; i < 4; i++) { int idx = t + 256 * i; up8(Wv[idx], &Wl[idx * 8]); }
    } else {
        const float4* Wv = (const float4*)Wr;
        #pragma unroll
        for (int i = 0; i < 8; i++) { int idx = t + 256 * i; ((float4*)Wl)[idx] = Wv[idx]; }
    }
    {
        const uint4* Xv = (const uint4*)h1b;
        #pragma unroll
        for (int i = 0; i < 2; i++) {
            int idx = t + 256 * i;
            int row = idx >> 4, col = (idx & 15) * 8;
            uint4 v = (r0 + row < N) ? Xv[(size_t)(r0 + row) * 16 + (idx & 15)] : uint4{0,0,0,0};
            float tmp[8]; up8(v, tmp);
            #pragma unroll
            for (int j = 0; j < 8; j++) Xl[row * 129 + col + j] = tmp[j];
        }
    }
    __syncthreads();
    int rg = t >> 4, cg = t & 15;
    float4 acc[2] = {{0,0,0,0},{0,0,0,0}};
    #pragma unroll 4
    for (int k = 0; k < 128; k++) {
        float4 w = *(const float4*)&Wl[k * 64 + (cg << 2)];
        #pragma unroll
        for (int i = 0; i < 2; i++) {
            float xv = Xl[(rg * 2 + i) * 129 + k];
            acc[i].x += xv * w.x; acc[i].y += xv * w.y;
            acc[i].z += xv * w.z; acc[i].w += xv * w.w;
        }
    }
    float aS0 = ldf(aSr, cg*4+0, bf), aS1 = ldf(aSr, cg*4+1, bf);
    float aS2 = ldf(aSr, cg*4+2, bf), aS3 = ldf(aSr, cg*4+3, bf);
    float aD0 = ldf(aDr, cg*4+0, bf), aD1 = ldf(aDr, cg*4+1, bf);
    float aD2 = ldf(aDr, cg*4+2, bf), aD3 = ldf(aDr, cg*4+3, bf);
    #pragma unroll
    for (int i = 0; i < 2; i++) {
        int row = r0 + rg * 2 + i;
        float ps = acc[i].x*aS0 + acc[i].y*aS1 + acc[i].z*aS2 + acc[i].w*aS3;
        float pd = acc[i].x*aD0 + acc[i].y*aD1 + acc[i].z*aD2 + acc[i].w*aD3;
        ps += __shfl_xor(ps, 1); ps += __shfl_xor(ps, 2);
        ps += __shfl_xor(ps, 4); ps += __shfl_xor(ps, 8);
        pd += __shfl_xor(pd, 1); pd += __shfl_xor(pd, 2);
        pd += __shfl_xor(pd, 4); pd += __shfl_xor(pd, 8);
        if (row < N) {
            if (cg == 0) { a_src[row] = ps; a_dst[row] = pd; }
            uint2 pk;
            pk.x = (unsigned int)f2b(acc[i].x) | ((unsigned int)f2b(acc[i].y) << 16);
            pk.y = (unsigned int)f2b(acc[i].z) | ((unsigned int)f2b(acc[i].w) << 16);
            ((uint2*)xh2b)[(size_t)row * 16 + cg] = pk;
        }
    }
}

// ---------- layer 2 softmax-aggregate -> output (readlane s AND ex: no LDS ops) ----------
__global__ __launch_bounds__(256)
void k_agg2(const int* __restrict__ rowptr, const int* __restrict__ esrc,
            const float* __restrict__ a_src, const float* __restrict__ a_dst,
            const unsigned int* __restrict__ xh2b, const void* __restrict__ bias,
            void* __restrict__ out, const int* __restrict__ flags, int N) {
    int node = blockIdx.x * 4 + (threadIdx.x >> 6);
    int lane = threadIdx.x & 63;
    if (node >= N) return;
    int bf = flags[0];
    int r0 = rowptr[node], r1 = rowptr[node + 1];
    int q = lane >> 3;
    float adst = a_dst[node];
    const unsigned short* xs = (const unsigned short*)xh2b;
    // prefetch chunk 0
    int pidx = r0 + q;
    bool pval = pidx < r1;
    int   s_next = pval ? esrc[pidx] : 0;
    float a_next = pval ? a_src[s_next] : 0.f;
    float den = 0.f, acc = 0.f;
    for (int e = r0; e < r1; e += 8) {
        int   s_mine = s_next;
        float a_cur  = a_next;
        bool  vcur   = (e + q) < r1;
        int idx2 = e + 8 + q;
        bool v2 = idx2 < r1;
        s_next = v2 ? esrc[idx2] : 0;
        a_next = v2 ? a_src[s_next] : 0.f;
        float v = a_cur + adst;
        v = v > 0.f ? v : 0.2f * v;
        float ex = vcur ? __expf(v) : 0.f;
        den += ex;
        #pragma unroll
        for (int q2 = 0; q2 < 8; q2++) {
            int   s_q  = __builtin_amdgcn_readlane(s_mine, q2 * 8);
            float ex_q = __uint_as_float(
                (unsigned int)__builtin_amdgcn_readlane(__float_as_uint(ex), q2 * 8));
            const unsigned short* rowp = xs + (size_t)s_q * 64;   // SGPR base
            acc += ex_q * b2f(rowp[lane]);
        }
    }
    // xor 8/16/32 flips slot bits (3..5): each slot counted once (8 lanes hold same den)
    den += __shfl_xor(den, 8);
    den += __shfl_xor(den, 16);
    den += __shfl_xor(den, 32);
    float o = acc / (den + 1e-16f) + ldf(bias, lane, bf);
    size_t oi = (size_t)node * 64 + lane;
    if (bf) ((unsigned short*)out)[oi] = f2b(o);
    else    ((float*)out)[oi] = o;
}

// ---------- launch ----------
extern "C" void kernel_launch(void* const* d_in, const int* in_sizes, int n_in,
                              void* d_out, int out_size, void* d_ws, size_t ws_size,
                              hipStream_t stream) {
    const void* x   = d_in[0];
    const int*  ei  = (const int*)d_in[1];
    const void* W1  = d_in[2];
    const void* aS1 = d_in[3];
    const void* aD1 = d_in[4];
    const void* b1  = d_in[5];
    const void* W2  = d_in[6];
    const void* aS2 = d_in[7];
    const void* aD2 = d_in[8];
    const void* b2v = d_in[9];

    const int N  = in_sizes[0] / 128;   // 50000
    const int E  = in_sizes[1] / 2;     // 800000
    const int Et = E + N;

    char* p = (char*)d_ws;
    auto alloc = [&](size_t bytes) -> char* {
        char* q = p; p += (bytes + 255) & ~(size_t)255; return q;
    };
    unsigned int* xh1b = (unsigned int*)alloc((size_t)N * 64 * 4);
    unsigned int* h1b  = (unsigned int*)alloc((size_t)N * 64 * 4);
    unsigned int* xh2b = (unsigned int*)alloc((size_t)N * 32 * 4);
    float* as1  = (float*)alloc((size_t)N * 8 * 4);
    float* ad1  = (float*)alloc((size_t)N * 8 * 4);
    float* as2  = (float*)alloc((size_t)N * 4);
    float* ad2  = (float*)alloc((size_t)N * 4);
    int* counts = (int*)alloc((size_t)N * 4);
    int* rowptr = (int*)alloc((size_t)(N + 1) * 4);
    int* eoff   = (int*)alloc((size_t)Et * 4);
    int* esrc   = (int*)alloc((size_t)Et * 4);
    int* bsums  = (int*)alloc(64 * 4);
    int* flags  = (int*)alloc(16 * 4);
    unsigned short* Wt1 = (unsigned short*)alloc(128 * 128 * 2);

    k_detect<<<1, 256, 0, stream>>>((const unsigned short*)x, ei, flags, W1, Wt1);
    hipMemsetAsync(counts, 0, (size_t)N * 4, stream);

    int HB = (Et + 255) / 256;
    k_hist<<<HB, 256, 0, stream>>>(ei, counts, eoff, flags, E, Et);
    int NB = (N + 1023) / 1024;
    k_scan1<<<NB, 256, 0, stream>>>(counts, rowptr, bsums, N);
    k_scan3<<<NB, 256, 0, stream>>>(rowptr, bsums, N, Et);
    k_scatter<<<HB, 256, 0, stream>>>(ei, rowptr, eoff, esrc, flags, E, Et);

    k_gemm1m<<<(N + 63) / 64, 256, 0, stream>>>(x, Wt1, aS1, aD1, xh1b, as1, ad1, flags, N);
    k_agg1<<<(N + 3) / 4, 256, 0, stream>>>(rowptr, esrc, as1, ad1, xh1b, b1, h1b, flags, N);
    int NGB = (N + 31) / 32;
    k_gemm2<<<NGB, 256, 0, stream>>>(h1b, W2, aS2, aD2, xh2b, as2, ad2, flags, N);
    k_agg2<<<(N + 3) / 4, 256, 0, stream>>>(rowptr, esrc, as2, ad2, xh2b, b2v, d_out, flags, N);
}